// Round 4
// baseline (763.320 us; speedup 1.0000x reference)
//
#include <hip/hip_runtime.h>
#include <cstdint>
#include <cstddef>

#define B_  32
#define L_  4096
#define FT_ 512
#define FS_ 512
#define H_  512
#define C_  1025   // FT + FS + 1
#define TL  64
#define NCH (L_ / TL)   // 64 l-chunks per batch row

typedef __attribute__((ext_vector_type(8))) short short8;   // 8 bf16 = 4 VGPRs
typedef __attribute__((ext_vector_type(4))) float float4v;  // MFMA C/D

// fp32 -> bf16 round-to-nearest-even
__device__ __forceinline__ short f2bf(float f) {
    union { float f; unsigned u; } v; v.f = f;
    unsigned r = v.u + 0x7FFF + ((v.u >> 16) & 1);
    return (short)(r >> 16);
}

// tanh(x) = 1 - 2/(e^2x + 1); graceful at +-inf (->+-1), cheap: exp + rcp.
__device__ __forceinline__ float fast_tanh(float x) {
    float e = __expf(2.f * x);
    return 1.f - 2.f * __builtin_amdgcn_rcpf(e + 1.f);
}

// ---------------------------------------------------------------------------
// Kernel 1 (fused prep): blocks [0,128) pack W1's text block into MFMA
// B-fragment order (bf16) + extract w1c + zero the per-b completion
// counters (ws is POISONED each iteration -- counters must be re-zeroed
// here, before logits launches; stream order guarantees visibility).
// Blocks [128, 128+1024): sconst[b][h] = b1[h] + W1[h,FT:FT+FS].summary[b];
// one wave per h-quad: wrow loaded once, reused across 4 b's.
// ---------------------------------------------------------------------------
__global__ __launch_bounds__(256) void prep_kernel(
        const float* __restrict__ W1, const float* __restrict__ summary,
        const float* __restrict__ b1, short* __restrict__ fragB,
        float* __restrict__ w1c, float* __restrict__ sconst,
        int* __restrict__ cnt) {
    if (blockIdx.x < 128) {
        int gid = blockIdx.x * 256 + threadIdx.x;   // granule id, 32768 total
        int lane = gid & 63;
        int ts_  = gid >> 6;        // t*16 + s
        int t = ts_ >> 4;
        int s = ts_ & 15;
        int h  = t * 16 + (lane & 15);
        int k0 = s * 32 + (lane >> 4) * 8;
        const float* src = W1 + (size_t)h * C_ + k0;
        short8 o;
        #pragma unroll
        for (int j = 0; j < 8; ++j) o[j] = f2bf(src[j]);
        *(short8*)(fragB + (size_t)gid * 8) = o;
        if (gid < H_) w1c[gid] = W1[(size_t)gid * C_ + FT_ + FS_];
        if (gid < B_) cnt[gid] = 0;                 // zero completion counters
    } else {
        int wid  = ((blockIdx.x - 128) * 256 + threadIdx.x) >> 6;  // 0..4095
        int lane = threadIdx.x & 63;
        int h  = wid & 511;
        int bq = wid >> 9;          // 0..7 -> b in [4bq, 4bq+4)
        const float* wrow = W1 + (size_t)h * C_ + FT_;
        float w[8];
        #pragma unroll
        for (int j = 0; j < 8; ++j) w[j] = wrow[lane + 64 * j];
        #pragma unroll
        for (int bi = 0; bi < 4; ++bi) {
            const int b = bq * 4 + bi;
            const float* srow = summary + (size_t)b * FS_;
            float acc = 0.f;
            #pragma unroll
            for (int j = 0; j < 8; ++j) acc += w[j] * srow[lane + 64 * j];
            #pragma unroll
            for (int off = 32; off > 0; off >>= 1) acc += __shfl_down(acc, off, 64);
            if (lane == 0) sconst[(size_t)b * H_ + h] = acc + b1[h];
        }
    }
}

// ---------------------------------------------------------------------------
// Kernel 2 (MFMA logits + fused context partial + LAST-BLOCK FINALIZE),
// TL=64, 512 threads, 8 waves x (64h nt=4, 64l mt=4), acc 16 float4v.
// 2 blocks/CU (LDS ~64KB, VGPR<=128 -> 4 waves/SIMD). A staged in 64 KB
// XOR-swizzled LDS; B-frags streamed from L2-resident fragB with 1-deep
// register prefetch. Epilogue -> logits + chunk softmax stats + cpart.
// Tail: device-scope release fence + atomicAdd(cnt[b]); the nv-th block
// for b runs the per-b finalize inline (stats reduce, attn row, ctx) --
// removes the separate finalize launch and overlaps its work with other
// b's logits blocks. FP order identical to the old finalize_kernel.
// ---------------------------------------------------------------------------
__global__ __launch_bounds__(512, 4) void logits_ctx_kernel(
        const float* __restrict__ ts, const float* __restrict__ coverage,
        const int* __restrict__ text_length,
        const short* __restrict__ fragB, const float* __restrict__ w1c,
        const float* __restrict__ sconst, const float* __restrict__ W2,
        const float* __restrict__ b2, float* __restrict__ logits,
        float2* __restrict__ stats_c, float* __restrict__ cpart,
        int* __restrict__ cnt, float* __restrict__ ctx,
        float* __restrict__ attn_out) {
    const int b  = blockIdx.y;
    const int l0 = blockIdx.x * TL;
    const int len = text_length[b];
    if (l0 >= len) return;   // uniform early-out before any barrier

    __shared__ short ts_lds[TL * 512];   // 64 KB, XOR-swizzled
    __shared__ float fin_sm[NCH];        // finalize: exp(m_c - m)
    __shared__ float fin_redm[8];
    __shared__ float fin_reds[8];
    __shared__ int   fin_flag;

    // ---- stage: 2 float4 -> 1 short8 per iter, granule-swizzled ----
    const float4* src = (const float4*)(ts + ((size_t)b * L_ + l0) * FT_);
    for (int j = threadIdx.x; j < TL * 64; j += 512) {
        int l = j >> 6;
        int g = j & 63;                 // 16B granule within row
        float4 v0 = src[2 * j];
        float4 v1 = src[2 * j + 1];
        short8 p;
        p[0] = f2bf(v0.x); p[1] = f2bf(v0.y); p[2] = f2bf(v0.z); p[3] = f2bf(v0.w);
        p[4] = f2bf(v1.x); p[5] = f2bf(v1.y); p[6] = f2bf(v1.z); p[7] = f2bf(v1.w);
        *(short8*)(ts_lds + l * 512 + ((g ^ (l & 7)) << 3)) = p;
    }
    __syncthreads();

    const int lane = threadIdx.x & 63;
    const int wv   = threadIdx.x >> 6;    // wave 0..7 -> h-chunk [64wv, 64wv+64)
    const int col  = lane & 15;
    const int quad = lane >> 4;
    const int swz  = col & 7;             // A-row swizzle key (row m = mt*16+col)

    const short* aBase = ts_lds + col * 512;                  // + mt*16*512
    const short* bBase = fragB + (size_t)(wv * 4) * 16 * 512 + lane * 8;

#define LDB(ntv, ksv) (*(const short8*)(bBase + (size_t)((ntv) * 16 + (ksv)) * 512))

    float4v acc[4][4];                    // [nt][mt]
    #pragma unroll
    for (int nt = 0; nt < 4; ++nt)
        #pragma unroll
        for (int mt = 0; mt < 4; ++mt)
            acc[nt][mt] = (float4v){0.f, 0.f, 0.f, 0.f};

    short8 bc0 = LDB(0, 0), bc1 = LDB(1, 0), bc2 = LDB(2, 0), bc3 = LDB(3, 0);

    for (int ks = 0; ks < 15; ++ks) {
        short8 af[4];
        const int ag = ((ks * 4 + quad) ^ swz) << 3;
        #pragma unroll
        for (int mt = 0; mt < 4; ++mt)
            af[mt] = *(const short8*)(aBase + mt * (16 * 512) + ag);
        // prefetch next ks (issues before MFMAs; latency hides under them)
        short8 bn0 = LDB(0, ks + 1), bn1 = LDB(1, ks + 1),
               bn2 = LDB(2, ks + 1), bn3 = LDB(3, ks + 1);
        #pragma unroll
        for (int mt = 0; mt < 4; ++mt)
            acc[0][mt] = __builtin_amdgcn_mfma_f32_16x16x32_bf16(af[mt], bc0, acc[0][mt], 0, 0, 0);
        #pragma unroll
        for (int mt = 0; mt < 4; ++mt)
            acc[1][mt] = __builtin_amdgcn_mfma_f32_16x16x32_bf16(af[mt], bc1, acc[1][mt], 0, 0, 0);
        #pragma unroll
        for (int mt = 0; mt < 4; ++mt)
            acc[2][mt] = __builtin_amdgcn_mfma_f32_16x16x32_bf16(af[mt], bc2, acc[2][mt], 0, 0, 0);
        #pragma unroll
        for (int mt = 0; mt < 4; ++mt)
            acc[3][mt] = __builtin_amdgcn_mfma_f32_16x16x32_bf16(af[mt], bc3, acc[3][mt], 0, 0, 0);
        bc0 = bn0; bc1 = bn1; bc2 = bn2; bc3 = bn3;
    }
    {   // ks = 15 tail (no prefetch)
        short8 af[4];
        const int ag = ((15 * 4 + quad) ^ swz) << 3;
        #pragma unroll
        for (int mt = 0; mt < 4; ++mt)
            af[mt] = *(const short8*)(aBase + mt * (16 * 512) + ag);
        #pragma unroll
        for (int mt = 0; mt < 4; ++mt)
            acc[0][mt] = __builtin_amdgcn_mfma_f32_16x16x32_bf16(af[mt], bc0, acc[0][mt], 0, 0, 0);
        #pragma unroll
        for (int mt = 0; mt < 4; ++mt)
            acc[1][mt] = __builtin_amdgcn_mfma_f32_16x16x32_bf16(af[mt], bc1, acc[1][mt], 0, 0, 0);
        #pragma unroll
        for (int mt = 0; mt < 4; ++mt)
            acc[2][mt] = __builtin_amdgcn_mfma_f32_16x16x32_bf16(af[mt], bc2, acc[2][mt], 0, 0, 0);
        #pragma unroll
        for (int mt = 0; mt < 4; ++mt)
            acc[3][mt] = __builtin_amdgcn_mfma_f32_16x16x32_bf16(af[mt], bc3, acc[3][mt], 0, 0, 0);
    }
#undef LDB

    // ---- epilogue: tanh-weighted h-reduction ----
    const int h0 = wv * 64;
    const float* sc_b = sconst + (size_t)b * H_;
    float4 cov[4];
    #pragma unroll
    for (int mt = 0; mt < 4; ++mt)
        cov[mt] = *(const float4*)(coverage + (size_t)b * L_ + l0 + mt * 16 + quad * 4);

    float partial[4][4];                  // [mt][r], l = mt*16 + quad*4 + r
    #pragma unroll
    for (int mt = 0; mt < 4; ++mt)
        #pragma unroll
        for (int r = 0; r < 4; ++r) partial[mt][r] = 0.f;

    #pragma unroll
    for (int nt = 0; nt < 4; ++nt) {
        const int h = h0 + nt * 16 + col;
        const float sc = sc_b[h];
        const float wc = w1c[h];
        const float w2 = W2[h];
        #pragma unroll
        for (int mt = 0; mt < 4; ++mt)
            #pragma unroll
            for (int r = 0; r < 4; ++r) {
                float pre = acc[nt][mt][r] + sc + wc * ((const float*)&cov[mt])[r];
                partial[mt][r] += w2 * fast_tanh(pre);
            }
    }

    #pragma unroll
    for (int mt = 0; mt < 4; ++mt)
        #pragma unroll
        for (int r = 0; r < 4; ++r) {
            float v = partial[mt][r];
            v += __shfl_xor(v, 8, 64);
            v += __shfl_xor(v, 4, 64);
            v += __shfl_xor(v, 2, 64);
            v += __shfl_xor(v, 1, 64);
            partial[mt][r] = v;
        }

    __syncthreads();                      // done with ts_lds A-data
    float* red  = (float*)ts_lds;         // 8 waves x 64 l partials (512 f)
    float* wbuf = red + 512;              // 64 chunk-local softmax weights
    if (col == 0) {
        #pragma unroll
        for (int mt = 0; mt < 4; ++mt)
            #pragma unroll
            for (int r = 0; r < 4; ++r)
                red[wv * 64 + mt * 16 + quad * 4 + r] = partial[mt][r];
    }
    __syncthreads();

    // ---- wave 0: final logits + chunk-local softmax stats/weights ----
    if (threadIdx.x < 64) {
        const int t = threadIdx.x;
        const bool valid = (l0 + t < len);
        float lg = b2[0];
        #pragma unroll
        for (int w = 0; w < 8; ++w) lg += red[w * 64 + t];
        logits[(size_t)b * L_ + l0 + t] = lg;
        float mv = valid ? lg : -INFINITY;
        #pragma unroll
        for (int off = 32; off > 0; off >>= 1)
            mv = fmaxf(mv, __shfl_xor(mv, off, 64));
        const float wt = valid ? __expf(lg - mv) : 0.f;
        float sv = wt;
        #pragma unroll
        for (int off = 32; off > 0; off >>= 1) sv += __shfl_xor(sv, off, 64);
        wbuf[t] = wt;
        if (t == 0) {
            float2 o; o.x = mv; o.y = sv;
            stats_c[(size_t)b * NCH + blockIdx.x] = o;
        }
    }
    __syncthreads();

    // ---- fused context partial: cpart[b][chunk][f] = sum_l w_l*ts[b,l,f] ----
    // ts rows were just staged -> L2-hot; fp32 keeps full context precision.
    const int lend = min(len - l0, TL);
    const float* tsb = ts + ((size_t)b * L_ + l0) * FT_ + threadIdx.x;
    float cx = 0.f;
    #pragma unroll 4
    for (int l = 0; l < lend; ++l) cx += wbuf[l] * tsb[(size_t)l * FT_];
    cpart[((size_t)b * NCH + blockIdx.x) * FT_ + threadIdx.x] = cx;

    // ---- last-block-per-b finalize ----
    const int nv = (len + TL - 1) / TL;   // valid chunks for this b
    __threadfence();                       // release: logits/stats_c/cpart
    __syncthreads();
    if (threadIdx.x == 0) {
        int old = atomicAdd(&cnt[b], 1);   // device-scope by default
        fin_flag = (old == nv - 1);
    }
    __syncthreads();
    if (!fin_flag) return;
    __threadfence();                       // acquire: see other blocks' data

    const int t = threadIdx.x;
    // A) global softmax stats from nv chunk stats
    float2 st; st.x = 0.f; st.y = 0.f;
    float mloc = -INFINITY;
    if (t < nv) { st = stats_c[(size_t)b * NCH + t]; mloc = st.x; }
    float v = mloc;
    #pragma unroll
    for (int off = 32; off > 0; off >>= 1) v = fmaxf(v, __shfl_xor(v, off, 64));
    if ((t & 63) == 0) fin_redm[t >> 6] = v;
    __syncthreads();
    float m = fin_redm[0];
    #pragma unroll
    for (int w = 1; w < 8; ++w) m = fmaxf(m, fin_redm[w]);

    float sume = 0.f;
    if (t < nv) {
        const float sc = __expf(st.x - m);
        fin_sm[t] = sc;
        sume = st.y * sc;
    }
    float sv = sume;
    #pragma unroll
    for (int off = 32; off > 0; off >>= 1) sv += __shfl_xor(sv, off, 64);
    if ((t & 63) == 0) fin_reds[t >> 6] = sv;
    __syncthreads();
    float tot = 0.f;
    #pragma unroll
    for (int w = 0; w < 8; ++w) tot += fin_reds[w];
    const float inv = 1.f / tot;

    // B) attention output (every slot written; masked -> 0)
    const float* lgrow = logits + (size_t)b * L_;
    float* arow = attn_out + (size_t)b * L_;
    #pragma unroll
    for (int i = 0; i < L_ / 512; ++i) {
        const int l = i * 512 + t;
        float a = 0.f;
        if (l < len) a = __expf(lgrow[l] - m) * inv;
        arow[l] = a;
    }

    // C) context reduce across chunks with exact rescale
    const float* cp = cpart + (size_t)b * NCH * FT_ + t;   // thread t <-> f=t
    float c = 0.f;
    #pragma unroll 4
    for (int ch = 0; ch < nv; ++ch) c += fin_sm[ch] * cp[(size_t)ch * FT_];
    ctx[(size_t)b * FT_ + t] = c * inv;
}

// ---------------------------------------------------------------------------
extern "C" void kernel_launch(void* const* d_in, const int* in_sizes, int n_in,
                              void* d_out, int out_size, void* d_ws, size_t ws_size,
                              hipStream_t stream) {
    const float* ts       = (const float*)d_in[0];  // [B,L,FT]
    const float* summary  = (const float*)d_in[1];  // [B,FS]
    const float* coverage = (const float*)d_in[2];  // [B,1,L]
    const float* W1       = (const float*)d_in[3];  // [H,C]
    const float* b1       = (const float*)d_in[4];  // [H]
    const float* W2       = (const float*)d_in[5];  // [1,H]
    const float* b2       = (const float*)d_in[6];  // [1]
    const int*   text_len = (const int*)d_in[7];    // [B]

    float* ctx_out  = (float*)d_out;                // [B,FT]
    float* attn_out = (float*)d_out + B_ * FT_;     // [B,1,L]

    // Workspace layout (bytes, 16B aligned)
    char* ws = (char*)d_ws;
    short*  fragB   = (short*)(ws);                 // 512 KB  @ 0
    float*  w1c     = (float*)(ws + 524288);        // 2 KB
    float*  sconst  = (float*)(ws + 526336);        // 64 KB
    float*  logits  = (float*)(ws + 591872);        // 512 KB
    float2* stats_c = (float2*)(ws + 1116160);      // 16 KB  (B*NCH float2)
    float*  cpart   = (float*)(ws + 1132544);       // 4 MB   (B*NCH*FT)
    int*    cnt     = (int*)(ws + 5326848);         // 128 B  per-b counters

    prep_kernel<<<128 + 1024, 256, 0, stream>>>(W1, summary, b1, fragB, w1c,
                                                sconst, cnt);
    logits_ctx_kernel<<<dim3(NCH, B_), 512, 0, stream>>>(
        ts, coverage, text_len, fragB, w1c, sconst, W2, b2, logits, stats_c,
        cpart, cnt, ctx_out, attn_out);
}

// Round 5
// 411.988 us; speedup vs baseline: 1.8528x; 1.8528x over previous
//
#include <hip/hip_runtime.h>
#include <cstdint>
#include <cstddef>

#define B_  32
#define L_  4096
#define FT_ 512
#define FS_ 512
#define H_  512
#define C_  1025   // FT + FS + 1
#define TL  32
#define NCH (L_ / TL)   // 128 l-chunks per batch row

typedef __attribute__((ext_vector_type(8))) short short8;   // 8 bf16 = 4 VGPRs
typedef __attribute__((ext_vector_type(4))) float float4v;  // MFMA C/D

// fp32 -> bf16 round-to-nearest-even
__device__ __forceinline__ short f2bf(float f) {
    union { float f; unsigned u; } v; v.f = f;
    unsigned r = v.u + 0x7FFF + ((v.u >> 16) & 1);
    return (short)(r >> 16);
}

// tanh(x) = 1 - 2/(e^2x + 1); graceful at +-inf (->+-1), cheap: exp + rcp.
__device__ __forceinline__ float fast_tanh(float x) {
    float e = __expf(2.f * x);
    return 1.f - 2.f * __builtin_amdgcn_rcpf(e + 1.f);
}

// ---------------------------------------------------------------------------
// Kernel 1 (fused prep): blocks [0,128) pack W1's text block into MFMA
// B-fragment order (bf16) + extract w1c. Blocks [128, 128+1024):
// sconst[b][h] = b1[h] + W1[h,FT:FT+FS].summary[b]; one wave per h,
// wrow loaded once into regs and reused across 4 b's.
// ---------------------------------------------------------------------------
__global__ __launch_bounds__(256) void prep_kernel(
        const float* __restrict__ W1, const float* __restrict__ summary,
        const float* __restrict__ b1, short* __restrict__ fragB,
        float* __restrict__ w1c, float* __restrict__ sconst) {
    if (blockIdx.x < 128) {
        int gid = blockIdx.x * 256 + threadIdx.x;   // granule id, 32768 total
        int lane = gid & 63;
        int ts_  = gid >> 6;        // t*16 + s
        int t = ts_ >> 4;
        int s = ts_ & 15;
        int h  = t * 16 + (lane & 15);
        int k0 = s * 32 + (lane >> 4) * 8;
        const float* src = W1 + (size_t)h * C_ + k0;
        short8 o;
        #pragma unroll
        for (int j = 0; j < 8; ++j) o[j] = f2bf(src[j]);
        *(short8*)(fragB + (size_t)gid * 8) = o;
        if (gid < H_) w1c[gid] = W1[(size_t)gid * C_ + FT_ + FS_];
    } else {
        int wid  = ((blockIdx.x - 128) * 256 + threadIdx.x) >> 6;  // 0..4095
        int lane = threadIdx.x & 63;
        int h  = wid & 511;
        int bq = wid >> 9;          // 0..7 -> b in [4bq, 4bq+4)
        const float* wrow = W1 + (size_t)h * C_ + FT_;
        float w[8];
        #pragma unroll
        for (int j = 0; j < 8; ++j) w[j] = wrow[lane + 64 * j];
        #pragma unroll
        for (int bi = 0; bi < 4; ++bi) {
            const int b = bq * 4 + bi;
            const float* srow = summary + (size_t)b * FS_;
            float acc = 0.f;
            #pragma unroll
            for (int j = 0; j < 8; ++j) acc += w[j] * srow[lane + 64 * j];
            #pragma unroll
            for (int off = 32; off > 0; off >>= 1) acc += __shfl_down(acc, off, 64);
            if (lane == 0) sconst[(size_t)b * H_ + h] = acc + b1[h];
        }
    }
}

// ---------------------------------------------------------------------------
// Kernel 2 (MFMA logits + fused context partial) -- the round-1 geometry
// (best measured: ~118 us inferred). Per block: 32-l tile, all 512 h across
// 4 waves (128 h each). A staged once in 32 KB XOR-swizzled LDS (4 blocks/CU
// at __launch_bounds__(256,4) -> 16 waves/CU; occupancy proved dominant over
// fragB-traffic reduction in rounds 2-3). B-frags streamed from L2-resident
// fragB. Epilogue: sconst/coverage/tanh/W2 fuse, 16-lane shfl reduce,
// cross-wave LDS reduce -> logits; chunk-local softmax stats + weights;
// context partial from L2-hot fp32 ts rows.
// ---------------------------------------------------------------------------
__global__ __launch_bounds__(256, 4) void logits_ctx_kernel(
        const float* __restrict__ ts, const float* __restrict__ coverage,
        const int* __restrict__ text_length,
        const short* __restrict__ fragB, const float* __restrict__ w1c,
        const float* __restrict__ sconst, const float* __restrict__ W2,
        const float* __restrict__ b2, float* __restrict__ logits,
        float2* __restrict__ stats_c, float* __restrict__ cpart) {
    const int b  = blockIdx.y;
    const int l0 = blockIdx.x * TL;
    const int len = text_length[b];
    if (l0 >= len) return;   // uniform early-out before any barrier

    __shared__ short ts_lds[TL * 512];   // 32 KB, XOR-swizzled

    // ---- stage: 2 float4 -> 1 short8 per iter, granule-swizzled ----
    const float4* src = (const float4*)(ts + ((size_t)b * L_ + l0) * FT_);
    for (int j = threadIdx.x; j < TL * 64; j += 256) {
        int l = j >> 6;
        int g = j & 63;                 // 16B granule within row
        float4 v0 = src[2 * j];
        float4 v1 = src[2 * j + 1];
        short8 p;
        p[0] = f2bf(v0.x); p[1] = f2bf(v0.y); p[2] = f2bf(v0.z); p[3] = f2bf(v0.w);
        p[4] = f2bf(v1.x); p[5] = f2bf(v1.y); p[6] = f2bf(v1.z); p[7] = f2bf(v1.w);
        *(short8*)(ts_lds + l * 512 + ((g ^ (l & 7)) << 3)) = p;
    }
    __syncthreads();

    const int lane = threadIdx.x & 63;
    const int wv   = threadIdx.x >> 6;    // wave 0..3 -> h-chunk [128wv,128wv+128)
    const int col  = lane & 15;
    const int quad = lane >> 4;
    const int swz  = col & 7;             // A-row swizzle key (row m = mt*16+col)

    const short* aBase = ts_lds + col * 512;                  // + mt*16*512
    const short* bBase = fragB + (size_t)(wv * 8) * 16 * 512 + lane * 8;

    float4v acc[8][2];                    // [nt][mt]
    #pragma unroll
    for (int nt = 0; nt < 8; ++nt)
        #pragma unroll
        for (int mt = 0; mt < 2; ++mt)
            acc[nt][mt] = (float4v){0.f, 0.f, 0.f, 0.f};

    #pragma unroll 2
    for (int ks = 0; ks < 16; ++ks) {
        short8 af[2];
        const int ag = ((ks * 4 + quad) ^ swz) << 3;
        #pragma unroll
        for (int mt = 0; mt < 2; ++mt)
            af[mt] = *(const short8*)(aBase + mt * (16 * 512) + ag);
        #pragma unroll
        for (int nt = 0; nt < 8; ++nt) {
            short8 bf = *(const short8*)(bBase + (size_t)(nt * 16 + ks) * 512);
            #pragma unroll
            for (int mt = 0; mt < 2; ++mt)
                acc[nt][mt] = __builtin_amdgcn_mfma_f32_16x16x32_bf16(
                    af[mt], bf, acc[nt][mt], 0, 0, 0);
        }
    }

    // ---- epilogue: tanh-weighted h-reduction ----
    const int h0 = wv * 128;
    const float* sc_b = sconst + (size_t)b * H_;
    float4 cov[2];
    #pragma unroll
    for (int mt = 0; mt < 2; ++mt)
        cov[mt] = *(const float4*)(coverage + (size_t)b * L_ + l0 + mt * 16 + quad * 4);

    float partial[2][4];                  // [mt][r], l = mt*16 + quad*4 + r
    #pragma unroll
    for (int mt = 0; mt < 2; ++mt)
        #pragma unroll
        for (int r = 0; r < 4; ++r) partial[mt][r] = 0.f;

    #pragma unroll
    for (int nt = 0; nt < 8; ++nt) {
        const int h = h0 + nt * 16 + col;
        const float sc = sc_b[h];
        const float wc = w1c[h];
        const float w2 = W2[h];
        #pragma unroll
        for (int mt = 0; mt < 2; ++mt)
            #pragma unroll
            for (int r = 0; r < 4; ++r) {
                float pre = acc[nt][mt][r] + sc + wc * ((const float*)&cov[mt])[r];
                partial[mt][r] += w2 * fast_tanh(pre);
            }
    }

    #pragma unroll
    for (int mt = 0; mt < 2; ++mt)
        #pragma unroll
        for (int r = 0; r < 4; ++r) {
            float v = partial[mt][r];
            v += __shfl_xor(v, 8, 64);
            v += __shfl_xor(v, 4, 64);
            v += __shfl_xor(v, 2, 64);
            v += __shfl_xor(v, 1, 64);
            partial[mt][r] = v;
        }

    __syncthreads();                      // done with ts_lds A-data
    float* red  = (float*)ts_lds;         // 4 waves x 32 l partials (128 f)
    float* wbuf = red + 128;              // 32 chunk-local softmax weights
    if (col == 0) {
        #pragma unroll
        for (int mt = 0; mt < 2; ++mt)
            #pragma unroll
            for (int r = 0; r < 4; ++r)
                red[wv * 32 + mt * 16 + quad * 4 + r] = partial[mt][r];
    }
    __syncthreads();

    // ---- wave 0: final logits + chunk-local softmax stats/weights ----
    if (threadIdx.x < 64) {
        const int t = threadIdx.x;
        float lg = 0.f;
        const bool valid = (t < 32) && (l0 + t < len);
        if (t < 32) {
            lg = b2[0];
            #pragma unroll
            for (int w = 0; w < 4; ++w) lg += red[w * 32 + t];
            logits[(size_t)b * L_ + l0 + t] = lg;
        }
        float mv = valid ? lg : -INFINITY;
        #pragma unroll
        for (int off = 32; off > 0; off >>= 1)
            mv = fmaxf(mv, __shfl_xor(mv, off, 64));
        const float wt = valid ? __expf(lg - mv) : 0.f;
        float sv = wt;
        #pragma unroll
        for (int off = 32; off > 0; off >>= 1) sv += __shfl_xor(sv, off, 64);
        if (t < 32) wbuf[t] = wt;
        if (t == 0) {
            float2 o; o.x = mv; o.y = sv;
            stats_c[(size_t)b * NCH + blockIdx.x] = o;
        }
    }
    __syncthreads();

    // ---- fused context partial: cpart[b][chunk][f] = sum_l w_l*ts[b,l,f] ----
    // ts rows were just staged -> L2-hot; fp32 keeps full context precision.
    const int lend = min(len - l0, TL);
    const float* tsbase = ts + ((size_t)b * L_ + l0) * FT_ + 2 * threadIdx.x;
    float cx = 0.f, cy = 0.f;
    for (int l = 0; l < lend; ++l) {
        const float wl = wbuf[l];
        const float2 v = *(const float2*)(tsbase + (size_t)l * FT_);
        cx += wl * v.x; cy += wl * v.y;
    }
    float2 o; o.x = cx; o.y = cy;
    *(float2*)(cpart + ((size_t)b * NCH + blockIdx.x) * FT_ + 2 * threadIdx.x) = o;
}

// ---------------------------------------------------------------------------
// Kernel 3 (finalize, WIDENED: 8 blocks per b x 256 thr = 256 blocks, one
// per CU -- old 32-block version was latency-bound, ~40 us of the stable
// 48 us finalize+gap residual). Each block redundantly computes the cheap
// global stats (<=128 chunk pairs), then owns attn slice [512j, 512j+512)
// and ctx feature slice [64j, 64j+64) with a 4-way chunk-split reduction.
// Only chunks c < ceil(len/TL) are read (others were never written).
// ---------------------------------------------------------------------------
__global__ __launch_bounds__(256) void finalize_kernel(
        const float* __restrict__ logits, const float2* __restrict__ stats_c,
        const float* __restrict__ cpart, const int* __restrict__ text_length,
        float* __restrict__ ctx, float* __restrict__ attn_out) {
    const int b   = blockIdx.y;
    const int j   = blockIdx.x;                   // 0..7 slice id
    const int len = text_length[b];
    const int nv  = (len + TL - 1) / TL;          // valid chunks, 1..128
    const int t   = threadIdx.x;
    __shared__ float sm[NCH];                     // exp(m_c - m)
    __shared__ float redm[4];
    __shared__ float reds[4];
    __shared__ float redc[256];

    // ---- global softmax stats (redundant per block; cheap) ----
    float2 st; st.x = 0.f; st.y = 0.f;
    float mloc = -INFINITY;
    if (t < nv) { st = stats_c[(size_t)b * NCH + t]; mloc = st.x; }
    float v = mloc;
    #pragma unroll
    for (int off = 32; off > 0; off >>= 1) v = fmaxf(v, __shfl_xor(v, off, 64));
    if ((t & 63) == 0) redm[t >> 6] = v;
    __syncthreads();
    float m = fmaxf(fmaxf(redm[0], redm[1]), fmaxf(redm[2], redm[3]));

    float sume = 0.f;
    if (t < nv) {
        const float sc = __expf(st.x - m);
        sm[t] = sc;
        sume = st.y * sc;
    }
    float sv = sume;
    #pragma unroll
    for (int off = 32; off > 0; off >>= 1) sv += __shfl_xor(sv, off, 64);
    if ((t & 63) == 0) reds[t >> 6] = sv;
    __syncthreads();                              // sm[] + reds[] visible
    const float tot = reds[0] + reds[1] + reds[2] + reds[3];
    const float inv = 1.f / tot;

    // ---- attention slice [512j, 512j+512): every slot written ----
    const float* lgrow = logits + (size_t)b * L_;
    float* arow = attn_out + (size_t)b * L_;
    #pragma unroll
    for (int i = 0; i < 2; ++i) {
        const int l = j * 512 + i * 256 + t;
        float a = 0.f;
        if (l < len) a = __expf(lgrow[l] - m) * inv;
        arow[l] = a;
    }

    // ---- ctx feature slice [64j, 64j+64): 4-way chunk split ----
    const int f  = j * 64 + (t & 63);
    const int cs = t >> 6;                        // chunk-split lane 0..3
    const float* cp = cpart + (size_t)b * NCH * FT_ + f;
    float c = 0.f;
    for (int ch = cs; ch < nv; ch += 4) c += sm[ch] * cp[(size_t)ch * FT_];
    redc[t] = c;
    __syncthreads();
    if (t < 64) {
        float cfin = (redc[t] + redc[t + 64]) + (redc[t + 128] + redc[t + 192]);
        ctx[(size_t)b * FT_ + j * 64 + t] = cfin * inv;
    }
}

// ---------------------------------------------------------------------------
extern "C" void kernel_launch(void* const* d_in, const int* in_sizes, int n_in,
                              void* d_out, int out_size, void* d_ws, size_t ws_size,
                              hipStream_t stream) {
    const float* ts       = (const float*)d_in[0];  // [B,L,FT]
    const float* summary  = (const float*)d_in[1];  // [B,FS]
    const float* coverage = (const float*)d_in[2];  // [B,1,L]
    const float* W1       = (const float*)d_in[3];  // [H,C]
    const float* b1       = (const float*)d_in[4];  // [H]
    const float* W2       = (const float*)d_in[5];  // [1,H]
    const float* b2       = (const float*)d_in[6];  // [1]
    const int*   text_len = (const int*)d_in[7];    // [B]

    float* ctx_out  = (float*)d_out;                // [B,FT]
    float* attn_out = (float*)d_out + B_ * FT_;     // [B,1,L]

    // Workspace layout (bytes, 16B aligned)
    char* ws = (char*)d_ws;
    short*  fragB   = (short*)(ws);                 // 512 KB  @ 0
    float*  w1c     = (float*)(ws + 524288);        // 2 KB
    float*  sconst  = (float*)(ws + 526336);        // 64 KB
    float*  logits  = (float*)(ws + 591872);        // 512 KB
    float2* stats_c = (float2*)(ws + 1116160);      // 32 KB  (B*NCH float2)
    float*  cpart   = (float*)(ws + 1148928);       // 8 MB   (B*NCH*FT)

    prep_kernel<<<128 + 1024, 256, 0, stream>>>(W1, summary, b1, fragB, w1c, sconst);
    logits_ctx_kernel<<<dim3(NCH, B_), 256, 0, stream>>>(
        ts, coverage, text_len, fragB, w1c, sconst, W2, b2, logits, stats_c, cpart);
    finalize_kernel<<<dim3(8, B_), 256, 0, stream>>>(
        logits, stats_c, cpart, text_len, ctx_out, attn_out);
}